// Round 1
// baseline (789.732 us; speedup 1.0000x reference)
//
#include <hip/hip_runtime.h>
#include <hip/hip_bf16.h>
#include <math.h>

#define B 64
#define NP 32
#define NS 72
#define NH 4
#define NF 64
#define HD 256
#define CTXD 112
#define NL 4
#define NC 110
#define LN_EPS 1e-6f
#define TI 8
#define GROWS 8

typedef __hip_bfloat16 bf16;

__device__ __forceinline__ float ldv(const float* p, int i) { return p[i]; }
__device__ __forceinline__ float ldv(const bf16* p, int i) { return __bfloat162float(p[i]); }
__device__ __forceinline__ void stv(float* p, int i, float v) { p[i] = v; }
__device__ __forceinline__ void stv(bf16* p, int i, float v) { p[i] = __float2bfloat16(v); }

// ---------- dtype detector: adj[0,0]==1.0 guaranteed (self-loop).
// bf16 1.0 -> first halfword 0x3F80 ; f32 1.0 -> first halfword 0x0000.
__global__ void k_detect(const void* adj, int* flag) {
  if (threadIdx.x == 0 && blockIdx.x == 0) {
    *flag = (((const unsigned short*)adj)[0] == 0x3F80u) ? 1 : 0;
  }
}

__device__ __forceinline__ void block_reduce_2(float& a, float& b, float* sred, int t) {
  #pragma unroll
  for (int o = 32; o > 0; o >>= 1) { a += __shfl_down(a, o); b += __shfl_down(b, o); }
  if ((t & 63) == 0) { sred[(t >> 6) * 2] = a; sred[(t >> 6) * 2 + 1] = b; }
  __syncthreads();
  a = sred[0] + sred[2] + sred[4] + sred[6];
  b = sred[1] + sred[3] + sred[5] + sred[7];
}

// ---------- context head: g = relu(LN(ctx @ ctx_W + ctx_b))
template <typename T>
__device__ void ctx_body(const T* cardctx, const T* ctxW, const T* ctxb,
                         const T* lncs, const T* lncb, float* g,
                         float* sred, float* sctx) {
  int b = blockIdx.x, t = threadIdx.x;
  if (t < CTXD) sctx[t] = ldv(cardctx, b * CTXD + t);
  __syncthreads();
  float acc = ldv(ctxb, t);
  for (int k = 0; k < CTXD; ++k) acc += sctx[k] * ldv(ctxW, k * HD + t);
  float a = acc, bb = acc * acc;
  block_reduce_2(a, bb, sred, t);
  float mean = a * (1.f / HD);
  float var = bb * (1.f / HD) - mean * mean;
  float r = rsqrtf(var + LN_EPS);
  float v = (acc - mean) * r * ldv(lncs, t) + ldv(lncb, t);
  g[b * HD + t] = fmaxf(v, 0.f);
}
__global__ void __launch_bounds__(256) k_ctx(const void* cardctx, const void* ctxW, const void* ctxb,
                      const void* lncs, const void* lncb, float* g, const int* flag) {
  __shared__ float sred[8];
  __shared__ float sctx[CTXD];
  if (*flag) ctx_body<bf16>((const bf16*)cardctx, (const bf16*)ctxW, (const bf16*)ctxb,
                            (const bf16*)lncs, (const bf16*)lncb, g, sred, sctx);
  else ctx_body<float>((const float*)cardctx, (const float*)ctxW, (const float*)ctxb,
                       (const float*)lncs, (const float*)lncb, g, sred, sctx);
}

// ---------- input projection: x[b,s,:] = sum_p spatial[b,p,s] * in_W[p,:] + in_b
template <typename T>
__device__ void inproj_body(const T* spat, const T* inW, const T* inb, float* x, float* ssp) {
  int blk = blockIdx.x; int b = blk / NS; int s = blk % NS; int t = threadIdx.x;
  if (t < NP) ssp[t] = ldv(spat, (b * NP + t) * NS + s);
  __syncthreads();
  float acc = ldv(inb, t);
  #pragma unroll 8
  for (int p = 0; p < NP; ++p) acc += ssp[p] * ldv(inW, p * HD + t);
  x[blk * HD + t] = acc;
}
__global__ void __launch_bounds__(256) k_inproj(const void* spat, const void* inW, const void* inb,
                         float* x, const int* flag) {
  __shared__ float ssp[NP];
  if (*flag) inproj_body<bf16>((const bf16*)spat, (const bf16*)inW, (const bf16*)inb, x, ssp);
  else inproj_body<float>((const float*)spat, (const float*)inW, (const float*)inb, x, ssp);
}

// ---------- per-layer context projection: c[b,:] = g[b,:] @ cp_W[l] + cp_b[l]
template <typename T>
__device__ void cproj_body(const float* g, const T* cpW, const T* cpb, float* c, int l, float* sg) {
  int b = blockIdx.x, t = threadIdx.x;
  sg[t] = g[b * HD + t];
  __syncthreads();
  const T* W = cpW + l * HD * HD;
  float acc = ldv(cpb, l * HD + t);
  for (int k = 0; k < HD; ++k) acc += sg[k] * ldv(W, k * HD + t);
  c[b * HD + t] = acc;
}
__global__ void __launch_bounds__(256) k_cproj(const float* g, const void* cpW, const void* cpb,
                        float* c, int l, const int* flag) {
  __shared__ float sg[HD];
  if (*flag) cproj_body<bf16>(g, (const bf16*)cpW, (const bf16*)cpb, c, l, sg);
  else cproj_body<float>(g, (const float*)cpW, (const float*)cpb, c, l, sg);
}

// ---------- h = LN(x)*s + b + c[b]
template <typename T>
__device__ void lnadd_body(const float* x, const float* c, const T* lnps, const T* lnpb,
                           float* h, int l, float* sred) {
  int row = blockIdx.x, t = threadIdx.x;
  float v = x[row * HD + t];
  float a = v, bb = v * v;
  block_reduce_2(a, bb, sred, t);
  float mean = a * (1.f / HD);
  float var = bb * (1.f / HD) - mean * mean;
  float r = rsqrtf(var + LN_EPS);
  float o = (v - mean) * r * ldv(lnps, l * HD + t) + ldv(lnpb, l * HD + t)
          + c[(row / NS) * HD + t];
  h[row * HD + t] = o;
}
__global__ void __launch_bounds__(256) k_lnadd(const float* x, const float* c, const void* lnps, const void* lnpb,
                        float* h, int l, const int* flag) {
  __shared__ float sred[8];
  if (*flag) lnadd_body<bf16>(x, c, (const bf16*)lnps, (const bf16*)lnpb, h, l, sred);
  else lnadd_body<float>(x, c, (const float*)lnps, (const float*)lnpb, h, l, sred);
}

// ---------- dual GEMM: hl = h @ Wl[l], hr = h @ Wr[l]  (8 rows per block)
template <typename T>
__device__ void gemmlr_body(const float* h, const T* Wl, const T* Wr, float* hl, float* hr,
                            int l, float (*xs)[HD]) {
  int row0 = blockIdx.x * GROWS; int t = threadIdx.x;
  #pragma unroll
  for (int r = 0; r < GROWS; ++r) xs[r][t] = h[(row0 + r) * HD + t];
  __syncthreads();
  const T* Wlp = Wl + l * HD * HD;
  const T* Wrp = Wr + l * HD * HD;
  float acc[GROWS];
  #pragma unroll
  for (int r = 0; r < GROWS; ++r) acc[r] = 0.f;
  for (int k = 0; k < HD; ++k) {
    float w = ldv(Wlp, k * HD + t);
    #pragma unroll
    for (int r = 0; r < GROWS; ++r) acc[r] += xs[r][k] * w;
  }
  #pragma unroll
  for (int r = 0; r < GROWS; ++r) hl[(row0 + r) * HD + t] = acc[r];
  #pragma unroll
  for (int r = 0; r < GROWS; ++r) acc[r] = 0.f;
  for (int k = 0; k < HD; ++k) {
    float w = ldv(Wrp, k * HD + t);
    #pragma unroll
    for (int r = 0; r < GROWS; ++r) acc[r] += xs[r][k] * w;
  }
  #pragma unroll
  for (int r = 0; r < GROWS; ++r) hr[(row0 + r) * HD + t] = acc[r];
}
__global__ void __launch_bounds__(256) k_gemm_lr(const float* h, const void* Wl, const void* Wr,
                          float* hl, float* hr, int l, const int* flag) {
  __shared__ float xs[GROWS][HD];
  if (*flag) gemmlr_body<bf16>(h, (const bf16*)Wl, (const bf16*)Wr, hl, hr, l, xs);
  else gemmlr_body<float>(h, (const float*)Wl, (const float*)Wr, hl, hr, l, xs);
}

// ---------- GATv2: scores -> masked softmax over j -> aggregate hr
template <typename T>
__device__ void gat_body(const float* hl, const float* hr, const T* adj, const T* Wa,
                         float* hg, int l, float (*shl)[HD], float* swa,
                         float (*ssc)[NH][NS]) {
  int blk = blockIdx.x; int b = blk / (NS / TI); int i0 = (blk % (NS / TI)) * TI;
  int t = threadIdx.x;
  swa[t] = ldv(Wa, l * HD + t);
  #pragma unroll
  for (int r = 0; r < TI; ++r) shl[r][t] = hl[(b * NS + i0 + r) * HD + t];
  __syncthreads();
  // scores: 2304 (r,h,j) tasks, 9 per thread
  for (int p = t; p < TI * NH * NS; p += 256) {
    int j = p % NS; int hh = (p / NS) % NH; int r = p / (NS * NH);
    const float* hrp = hr + (b * NS + j) * HD + hh * NF;
    const float* hlp = &shl[r][hh * NF];
    const float* wap = &swa[hh * NF];
    float sum = 0.f;
    #pragma unroll 8
    for (int f = 0; f < NF; ++f) {
      float e = hlp[f] + hrp[f];
      e = (e > 0.f) ? e : 0.2f * e;
      sum += e * wap[f];
    }
    ssc[r][hh][j] = sum;
  }
  __syncthreads();
  // softmax: 32 (r,h) tasks, one wave each (lane covers j and j+64)
  int wid = t >> 6, lane = t & 63;
  for (int task = wid; task < TI * NH; task += 4) {
    int r = task >> 2; int hh = task & 3;
    int i = i0 + r;
    float a1 = ldv(adj, i * NS + lane);
    float s1 = (a1 > 0.f) ? ssc[r][hh][lane] : -1e30f;
    float s2 = -1e30f;
    if (lane < NS - 64) {
      float a2 = ldv(adj, i * NS + 64 + lane);
      if (a2 > 0.f) s2 = ssc[r][hh][64 + lane];
    }
    float m = fmaxf(s1, s2);
    #pragma unroll
    for (int o = 32; o > 0; o >>= 1) m = fmaxf(m, __shfl_xor(m, o));
    float e1 = (s1 > -1e29f) ? __expf(s1 - m) : 0.f;
    float e2 = (s2 > -1e29f) ? __expf(s2 - m) : 0.f;
    float se = e1 + e2;
    #pragma unroll
    for (int o = 32; o > 0; o >>= 1) se += __shfl_xor(se, o);
    float inv = 1.f / se;
    ssc[r][hh][lane] = e1 * inv;
    if (lane < NS - 64) ssc[r][hh][64 + lane] = e2 * inv;
  }
  __syncthreads();
  // aggregate: out[i,h,f] = sum_j attn[i,h,j] * hr[j,h,f]; t == channel
  int hh = t >> 6;
  float acc[TI];
  #pragma unroll
  for (int r = 0; r < TI; ++r) acc[r] = 0.f;
  for (int j = 0; j < NS; ++j) {
    float hv = hr[(b * NS + j) * HD + t];
    #pragma unroll
    for (int r = 0; r < TI; ++r) acc[r] += ssc[r][hh][j] * hv;
  }
  #pragma unroll
  for (int r = 0; r < TI; ++r) hg[(b * NS + i0 + r) * HD + t] = acc[r];
}
__global__ void __launch_bounds__(256) k_gat(const float* hl, const float* hr, const void* adj, const void* Wa,
                      float* hg, int l, const int* flag) {
  __shared__ float shl[TI][HD];
  __shared__ float swa[HD];
  __shared__ float ssc[TI][NH][NS];
  if (*flag) gat_body<bf16>(hl, hr, (const bf16*)adj, (const bf16*)Wa, hg, l, shl, swa, ssc);
  else gat_body<float>(hl, hr, (const float*)adj, (const float*)Wa, hg, l, shl, swa, ssc);
}

// ---------- op GEMM accumulate: x += hg @ op_W[l] + op_b[l]
template <typename T>
__device__ void gemmop_body(const float* hg, const T* opW, const T* opb, float* x,
                            int l, float (*xs)[HD]) {
  int row0 = blockIdx.x * GROWS; int t = threadIdx.x;
  #pragma unroll
  for (int r = 0; r < GROWS; ++r) xs[r][t] = hg[(row0 + r) * HD + t];
  __syncthreads();
  const T* W = opW + l * HD * HD;
  float acc[GROWS];
  #pragma unroll
  for (int r = 0; r < GROWS; ++r) acc[r] = 0.f;
  for (int k = 0; k < HD; ++k) {
    float w = ldv(W, k * HD + t);
    #pragma unroll
    for (int r = 0; r < GROWS; ++r) acc[r] += xs[r][k] * w;
  }
  float bias = ldv(opb, l * HD + t);
  #pragma unroll
  for (int r = 0; r < GROWS; ++r) x[(row0 + r) * HD + t] += acc[r] + bias;
}
__global__ void __launch_bounds__(256) k_gemm_op(const float* hg, const void* opW, const void* opb,
                          float* x, int l, const int* flag) {
  __shared__ float xs[GROWS][HD];
  if (*flag) gemmop_body<bf16>(hg, (const bf16*)opW, (const bf16*)opb, x, l, xs);
  else gemmop_body<float>(hg, (const float*)opW, (const float*)opb, x, l, xs);
}

// ---------- heads: ge = mean_s x; five output heads
template <typename T>
__device__ void heads_body(const float* x,
                           const T* cardW, const T* cardb, const T* atW, const T* atb,
                           const T* srcW, const T* srcb, const T* tgtW, const T* tgtb,
                           const T* v1W, const T* v1b, const T* v2W, const T* v2b,
                           T* out, float* sge, float* sh1) {
  int b = blockIdx.x, t = threadIdx.x;
  float acc = 0.f;
  for (int s = 0; s < NS; ++s) acc += x[(b * NS + s) * HD + t];
  sge[t] = acc * (1.f / NS);
  __syncthreads();
  for (int p = t; p < NC + 3 + NS + NS; p += 256) {
    if (p < NC) {
      int col = p;
      float o = ldv(cardb, col);
      for (int k = 0; k < HD; ++k) o += sge[k] * ldv(cardW, k * NC + col);
      stv(out, b * NC + col, o);
    } else if (p < NC + 3) {
      int col = p - NC;
      float o = ldv(atb, col);
      for (int k = 0; k < HD; ++k) o += sge[k] * ldv(atW, k * 3 + col);
      stv(out, B * NC + b * 3 + col, o);
    } else if (p < NC + 3 + NS) {
      int col = p - NC - 3;
      float o = ldv(srcb, col);
      for (int k = 0; k < HD; ++k) o += sge[k] * ldv(srcW, k * NS + col);
      stv(out, B * NC + B * 3 + b * NS + col, o);
    } else {
      int col = p - NC - 3 - NS;
      float o = ldv(tgtb, col);
      for (int k = 0; k < HD; ++k) o += sge[k] * ldv(tgtW, k * NS + col);
      stv(out, B * NC + B * 3 + B * NS + b * NS + col, o);
    }
  }
  if (t < 128) {
    float o = ldv(v1b, t);
    for (int k = 0; k < HD; ++k) o += sge[k] * ldv(v1W, k * 128 + t);
    sh1[t] = fmaxf(o, 0.f);
  }
  __syncthreads();
  if (t < 64) {
    float pv = sh1[t] * ldv(v2W, t) + sh1[t + 64] * ldv(v2W, t + 64);
    #pragma unroll
    for (int o = 32; o > 0; o >>= 1) pv += __shfl_xor(pv, o);
    if (t == 0) stv(out, B * (NC + 3 + NS + NS) + b, tanhf(pv + ldv(v2b, 0)));
  }
}
__global__ void __launch_bounds__(256) k_heads(const float* x,
                        const void* cardW, const void* cardb, const void* atW, const void* atb,
                        const void* srcW, const void* srcb, const void* tgtW, const void* tgtb,
                        const void* v1W, const void* v1b, const void* v2W, const void* v2b,
                        void* out, const int* flag) {
  __shared__ float sge[HD];
  __shared__ float sh1[128];
  if (*flag) heads_body<bf16>(x, (const bf16*)cardW, (const bf16*)cardb, (const bf16*)atW,
                              (const bf16*)atb, (const bf16*)srcW, (const bf16*)srcb,
                              (const bf16*)tgtW, (const bf16*)tgtb, (const bf16*)v1W,
                              (const bf16*)v1b, (const bf16*)v2W, (const bf16*)v2b,
                              (bf16*)out, sge, sh1);
  else heads_body<float>(x, (const float*)cardW, (const float*)cardb, (const float*)atW,
                         (const float*)atb, (const float*)srcW, (const float*)srcb,
                         (const float*)tgtW, (const float*)tgtb, (const float*)v1W,
                         (const float*)v1b, (const float*)v2W, (const float*)v2b,
                         (float*)out, sge, sh1);
}

extern "C" void kernel_launch(void* const* d_in, const int* in_sizes, int n_in,
                              void* d_out, int out_size, void* d_ws, size_t ws_size,
                              hipStream_t stream) {
  const void* spatial = d_in[0];
  const void* cardctx = d_in[1];
  const void* adj = d_in[2];
  const void* ctxW = d_in[3]; const void* ctxb = d_in[4];
  const void* lncs = d_in[5]; const void* lncb = d_in[6];
  const void* inW = d_in[7];  const void* inb = d_in[8];
  const void* lnps = d_in[9]; const void* lnpb = d_in[10];
  const void* cpW = d_in[11]; const void* cpb = d_in[12];
  const void* Wl = d_in[13];  const void* Wr = d_in[14]; const void* Wa = d_in[15];
  const void* opW = d_in[16]; const void* opb = d_in[17];
  const void* cardW = d_in[18]; const void* cardb = d_in[19];
  const void* atW = d_in[20];   const void* atb = d_in[21];
  const void* srcW = d_in[22];  const void* srcb = d_in[23];
  const void* tgtW = d_in[24];  const void* tgtb = d_in[25];
  const void* v1W = d_in[26];   const void* v1b = d_in[27];
  const void* v2W = d_in[28];   const void* v2b = d_in[29];

  int* flag = (int*)d_ws;
  float* base = (float*)((char*)d_ws + 256);
  float* g  = base;               // B*HD
  float* c  = g + B * HD;         // B*HD
  float* x  = c + B * HD;         // B*NS*HD
  float* h  = x + B * NS * HD;    // B*NS*HD (reused as hg)
  float* hl = h + B * NS * HD;    // B*NS*HD
  float* hr = hl + B * NS * HD;   // B*NS*HD
  float* hg = h;                  // alias: h is dead once hl/hr exist

  k_detect<<<1, 64, 0, stream>>>(adj, flag);
  k_ctx<<<B, HD, 0, stream>>>(cardctx, ctxW, ctxb, lncs, lncb, g, flag);
  k_inproj<<<B * NS, HD, 0, stream>>>(spatial, inW, inb, x, flag);
  for (int l = 0; l < NL; ++l) {
    k_cproj<<<B, HD, 0, stream>>>(g, cpW, cpb, c, l, flag);
    k_lnadd<<<B * NS, HD, 0, stream>>>(x, c, lnps, lnpb, h, l, flag);
    k_gemm_lr<<<B * NS / GROWS, HD, 0, stream>>>(h, Wl, Wr, hl, hr, l, flag);
    k_gat<<<B * (NS / TI), HD, 0, stream>>>(hl, hr, adj, Wa, hg, l, flag);
    k_gemm_op<<<B * NS / GROWS, HD, 0, stream>>>(hg, opW, opb, x, l, flag);
  }
  k_heads<<<B, HD, 0, stream>>>(x, cardW, cardb, atW, atb, srcW, srcb, tgtW, tgtb,
                                v1W, v1b, v2W, v2b, d_out, flag);
}

// Round 2
// 652.677 us; speedup vs baseline: 1.2100x; 1.2100x over previous
//
#include <hip/hip_runtime.h>
#include <hip/hip_bf16.h>
#include <math.h>

#define B 64
#define NP 32
#define NS 72
#define NH 4
#define NF 64
#define HD 256
#define CTXD 112
#define NL 4
#define NC 110
#define LN_EPS 1e-6f
#define GROWS 8

// LDS strides for gat
#define SH 68   // hl_s / hr_s row stride (floats): even, b128-aligned, 2-way banks on lane reads
#define SA 76   // attnT row stride: multiple of 4 for float4 reads

typedef __hip_bfloat16 bf16;

__device__ __forceinline__ float ldv(const float* p, int i) { return p[i]; }
__device__ __forceinline__ float ldv(const bf16* p, int i) { return __bfloat162float(p[i]); }
__device__ __forceinline__ void stv(float* p, int i, float v) { p[i] = v; }
__device__ __forceinline__ void stv(bf16* p, int i, float v) { p[i] = __float2bfloat16(v); }

// ---------- dtype detector: adj[0,0]==1.0 guaranteed (self-loop).
__global__ void k_detect(const void* adj, int* flag) {
  if (threadIdx.x == 0 && blockIdx.x == 0) {
    *flag = (((const unsigned short*)adj)[0] == 0x3F80u) ? 1 : 0;
  }
}

__device__ __forceinline__ void block_reduce_2(float& a, float& b, float* sred, int t) {
  #pragma unroll
  for (int o = 32; o > 0; o >>= 1) { a += __shfl_down(a, o); b += __shfl_down(b, o); }
  if ((t & 63) == 0) { sred[(t >> 6) * 2] = a; sred[(t >> 6) * 2 + 1] = b; }
  __syncthreads();
  a = sred[0] + sred[2] + sred[4] + sred[6];
  b = sred[1] + sred[3] + sred[5] + sred[7];
}

// ---------- context head: g = relu(LN(ctx @ ctx_W + ctx_b))
template <typename T>
__device__ void ctx_body(const T* cardctx, const T* ctxW, const T* ctxb,
                         const T* lncs, const T* lncb, float* g,
                         float* sred, float* sctx) {
  int b = blockIdx.x, t = threadIdx.x;
  if (t < CTXD) sctx[t] = ldv(cardctx, b * CTXD + t);
  __syncthreads();
  float acc = ldv(ctxb, t);
  for (int k = 0; k < CTXD; ++k) acc += sctx[k] * ldv(ctxW, k * HD + t);
  float a = acc, bb = acc * acc;
  block_reduce_2(a, bb, sred, t);
  float mean = a * (1.f / HD);
  float var = bb * (1.f / HD) - mean * mean;
  float r = rsqrtf(var + LN_EPS);
  float v = (acc - mean) * r * ldv(lncs, t) + ldv(lncb, t);
  g[b * HD + t] = fmaxf(v, 0.f);
}
__global__ void __launch_bounds__(256) k_ctx(const void* cardctx, const void* ctxW, const void* ctxb,
                      const void* lncs, const void* lncb, float* g, const int* flag) {
  __shared__ float sred[8];
  __shared__ float sctx[CTXD];
  if (*flag) ctx_body<bf16>((const bf16*)cardctx, (const bf16*)ctxW, (const bf16*)ctxb,
                            (const bf16*)lncs, (const bf16*)lncb, g, sred, sctx);
  else ctx_body<float>((const float*)cardctx, (const float*)ctxW, (const float*)ctxb,
                       (const float*)lncs, (const float*)lncb, g, sred, sctx);
}

// ---------- input projection
template <typename T>
__device__ void inproj_body(const T* spat, const T* inW, const T* inb, float* x, float* ssp) {
  int blk = blockIdx.x; int b = blk / NS; int s = blk % NS; int t = threadIdx.x;
  if (t < NP) ssp[t] = ldv(spat, (b * NP + t) * NS + s);
  __syncthreads();
  float acc = ldv(inb, t);
  #pragma unroll 8
  for (int p = 0; p < NP; ++p) acc += ssp[p] * ldv(inW, p * HD + t);
  x[blk * HD + t] = acc;
}
__global__ void __launch_bounds__(256) k_inproj(const void* spat, const void* inW, const void* inb,
                         float* x, const int* flag) {
  __shared__ float ssp[NP];
  if (*flag) inproj_body<bf16>((const bf16*)spat, (const bf16*)inW, (const bf16*)inb, x, ssp);
  else inproj_body<float>((const float*)spat, (const float*)inW, (const float*)inb, x, ssp);
}

// ---------- per-layer context projection
template <typename T>
__device__ void cproj_body(const float* g, const T* cpW, const T* cpb, float* c, int l, float* sg) {
  int b = blockIdx.x, t = threadIdx.x;
  sg[t] = g[b * HD + t];
  __syncthreads();
  const T* W = cpW + l * HD * HD;
  float acc = ldv(cpb, l * HD + t);
  for (int k = 0; k < HD; ++k) acc += sg[k] * ldv(W, k * HD + t);
  c[b * HD + t] = acc;
}
__global__ void __launch_bounds__(256) k_cproj(const float* g, const void* cpW, const void* cpb,
                        float* c, int l, const int* flag) {
  __shared__ float sg[HD];
  if (*flag) cproj_body<bf16>(g, (const bf16*)cpW, (const bf16*)cpb, c, l, sg);
  else cproj_body<float>(g, (const float*)cpW, (const float*)cpb, c, l, sg);
}

// ---------- h = LN(x)*s + b + c[b]
template <typename T>
__device__ void lnadd_body(const float* x, const float* c, const T* lnps, const T* lnpb,
                           float* h, int l, float* sred) {
  int row = blockIdx.x, t = threadIdx.x;
  float v = x[row * HD + t];
  float a = v, bb = v * v;
  block_reduce_2(a, bb, sred, t);
  float mean = a * (1.f / HD);
  float var = bb * (1.f / HD) - mean * mean;
  float r = rsqrtf(var + LN_EPS);
  float o = (v - mean) * r * ldv(lnps, l * HD + t) + ldv(lnpb, l * HD + t)
          + c[(row / NS) * HD + t];
  h[row * HD + t] = o;
}
__global__ void __launch_bounds__(256) k_lnadd(const float* x, const float* c, const void* lnps, const void* lnpb,
                        float* h, int l, const int* flag) {
  __shared__ float sred[8];
  if (*flag) lnadd_body<bf16>(x, c, (const bf16*)lnps, (const bf16*)lnpb, h, l, sred);
  else lnadd_body<float>(x, c, (const float*)lnps, (const float*)lnpb, h, l, sred);
}

// ---------- dual GEMM: hl = h @ Wl[l], hr = h @ Wr[l]
template <typename T>
__device__ void gemmlr_body(const float* h, const T* Wl, const T* Wr, float* hl, float* hr,
                            int l, float (*xs)[HD]) {
  int row0 = blockIdx.x * GROWS; int t = threadIdx.x;
  #pragma unroll
  for (int r = 0; r < GROWS; ++r) xs[r][t] = h[(row0 + r) * HD + t];
  __syncthreads();
  const T* Wlp = Wl + l * HD * HD;
  const T* Wrp = Wr + l * HD * HD;
  float acc[GROWS];
  #pragma unroll
  for (int r = 0; r < GROWS; ++r) acc[r] = 0.f;
  for (int k = 0; k < HD; ++k) {
    float w = ldv(Wlp, k * HD + t);
    #pragma unroll
    for (int r = 0; r < GROWS; ++r) acc[r] += xs[r][k] * w;
  }
  #pragma unroll
  for (int r = 0; r < GROWS; ++r) hl[(row0 + r) * HD + t] = acc[r];
  #pragma unroll
  for (int r = 0; r < GROWS; ++r) acc[r] = 0.f;
  for (int k = 0; k < HD; ++k) {
    float w = ldv(Wrp, k * HD + t);
    #pragma unroll
    for (int r = 0; r < GROWS; ++r) acc[r] += xs[r][k] * w;
  }
  #pragma unroll
  for (int r = 0; r < GROWS; ++r) hr[(row0 + r) * HD + t] = acc[r];
}
__global__ void __launch_bounds__(256) k_gemm_lr(const float* h, const void* Wl, const void* Wr,
                          float* hl, float* hr, int l, const int* flag) {
  __shared__ float xs[GROWS][HD];
  if (*flag) gemmlr_body<bf16>(h, (const bf16*)Wl, (const bf16*)Wr, hl, hr, l, xs);
  else gemmlr_body<float>(h, (const float*)Wl, (const float*)Wr, hl, hr, l, xs);
}

// ---------- GATv2 v2: block = (b, head). LDS-staged hl/hr head slices,
// hr rows in registers, score = 0.6(A_i+B_j) + 0.4*sum_f wa|hl+hr|.
template <typename T>
__device__ void gat_body(const float* __restrict__ hl, const float* __restrict__ hr,
                         const T* __restrict__ adj, const T* __restrict__ Wa,
                         float* __restrict__ hg, int l,
                         float* hl_s, float* hr_s, float* attnT, float* wa04_s) {
  const int bid = blockIdx.x;
  const int b = bid >> 2, hh = bid & 3;
  const int t = threadIdx.x;
  const int w = t >> 6, L = t & 63;

  const float* hlbase = hl + (size_t)(b * NS) * HD + hh * NF;
  const float* hrbase = hr + (size_t)(b * NS) * HD + hh * NF;

  // hr rows -> registers: lane L owns row L (and tail row 64+(L&7))
  const float4* hrg1 = (const float4*)(hrbase + L * HD);
  const float4* hrg2 = (const float4*)(hrbase + (64 + (L & 7)) * HD);
  float4 hr1[16], hr2[16];
  #pragma unroll
  for (int q = 0; q < 16; ++q) hr1[q] = hrg1[q];
  #pragma unroll
  for (int q = 0; q < 16; ++q) hr2[q] = hrg2[q];

  // wa04 = 0.4 * Wa[l, hh, :]
  if (t < NF) wa04_s[t] = 0.4f * ldv(Wa, l * HD + hh * NF + t);

  // stage hl_s, hr_s head slices [72][SH], coalesced float4
  const float4* hlg4 = (const float4*)hlbase;
  const float4* hrg4 = (const float4*)hrbase;
  for (int c = t; c < NS * 16; c += 256) {
    int j = c >> 4, q = c & 15;
    *(float4*)&hl_s[j * SH + 4 * q] = hlg4[j * 64 + q];
    *(float4*)&hr_s[j * SH + 4 * q] = hrg4[j * 64 + q];
  }
  __syncthreads();

  // B15 = 0.6 * sum_f wa * hr_row  (per lane, from registers)
  float B1 = 0.f, B2 = 0.f;
  #pragma unroll
  for (int q = 0; q < 16; ++q) {
    float4 w4 = *(const float4*)&wa04_s[4 * q];
    B1 = fmaf(w4.x, hr1[q].x, B1); B1 = fmaf(w4.y, hr1[q].y, B1);
    B1 = fmaf(w4.z, hr1[q].z, B1); B1 = fmaf(w4.w, hr1[q].w, B1);
    B2 = fmaf(w4.x, hr2[q].x, B2); B2 = fmaf(w4.y, hr2[q].y, B2);
    B2 = fmaf(w4.z, hr2[q].z, B2); B2 = fmaf(w4.w, hr2[q].w, B2);
  }
  float B15_1 = 1.5f * B1, B15_2 = 1.5f * B2;
  float wa04L = wa04_s[L];

  // score + softmax: wave w handles i = w + 4p
  for (int p = 0; p < 18; ++p) {
    int i = w + 4 * p;
    // A15 = 0.6 * sum_f wa * hl_i  via lane-parallel dot + butterfly
    float av = wa04L * hl_s[i * SH + L];
    #pragma unroll
    for (int o = 32; o > 0; o >>= 1) av += __shfl_xor(av, o);
    float A15 = 1.5f * av;

    float acc1 = 0.f, acc2 = 0.f;
    #pragma unroll
    for (int q = 0; q < 16; ++q) {
      float4 h4 = *(const float4*)&hl_s[i * SH + 4 * q];
      float4 w4 = *(const float4*)&wa04_s[4 * q];
      float e;
      e = h4.x + hr1[q].x; acc1 = fmaf(w4.x, fabsf(e), acc1);
      e = h4.y + hr1[q].y; acc1 = fmaf(w4.y, fabsf(e), acc1);
      e = h4.z + hr1[q].z; acc1 = fmaf(w4.z, fabsf(e), acc1);
      e = h4.w + hr1[q].w; acc1 = fmaf(w4.w, fabsf(e), acc1);
      e = h4.x + hr2[q].x; acc2 = fmaf(w4.x, fabsf(e), acc2);
      e = h4.y + hr2[q].y; acc2 = fmaf(w4.y, fabsf(e), acc2);
      e = h4.z + hr2[q].z; acc2 = fmaf(w4.z, fabsf(e), acc2);
      e = h4.w + hr2[q].w; acc2 = fmaf(w4.w, fabsf(e), acc2);
    }
    float s1 = A15 + B15_1 + acc1;
    float s2 = A15 + B15_2 + acc2;
    float a1 = ldv(adj, i * NS + L);
    s1 = (a1 > 0.f) ? s1 : -1e30f;
    if (L < 8) {
      float a2 = ldv(adj, i * NS + 64 + L);
      s2 = (a2 > 0.f) ? s2 : -1e30f;
    } else {
      s2 = -1e30f;
    }
    float m = fmaxf(s1, s2);
    #pragma unroll
    for (int o = 32; o > 0; o >>= 1) m = fmaxf(m, __shfl_xor(m, o));
    float e1 = __expf(s1 - m);
    float e2 = __expf(s2 - m);
    float se = e1 + e2;
    #pragma unroll
    for (int o = 32; o > 0; o >>= 1) se += __shfl_xor(se, o);
    float inv = 1.f / se;
    attnT[L * SA + i] = e1 * inv;
    if (L < 8) attnT[(64 + L) * SA + i] = e2 * inv;
  }
  __syncthreads();

  // aggregation: out[i, f=L] = sum_j attnT[j][i] * hr_s[j][L]
  for (int p = 0; p < 5; ++p) {
    int g = w + 4 * p;
    if (g >= 18) break;
    int i0 = 4 * g;
    float a0 = 0.f, a1 = 0.f, a2 = 0.f, a3 = 0.f;
    #pragma unroll 4
    for (int j = 0; j < NS; ++j) {
      float4 at = *(const float4*)&attnT[j * SA + i0];
      float hv = hr_s[j * SH + L];
      a0 = fmaf(at.x, hv, a0); a1 = fmaf(at.y, hv, a1);
      a2 = fmaf(at.z, hv, a2); a3 = fmaf(at.w, hv, a3);
    }
    float* o = hg + (size_t)(b * NS + i0) * HD + hh * NF + L;
    o[0] = a0; o[HD] = a1; o[2 * HD] = a2; o[3 * HD] = a3;
  }
}
__global__ void __launch_bounds__(256, 1) k_gat(const float* hl, const float* hr, const void* adj, const void* Wa,
                      float* hg, int l, const int* flag) {
  __shared__ float hl_s[NS * SH];
  __shared__ float hr_s[NS * SH];
  __shared__ float attnT[NS * SA];
  __shared__ float wa04_s[NF];
  if (*flag) gat_body<bf16>(hl, hr, (const bf16*)adj, (const bf16*)Wa, hg, l, hl_s, hr_s, attnT, wa04_s);
  else gat_body<float>(hl, hr, (const float*)adj, (const float*)Wa, hg, l, hl_s, hr_s, attnT, wa04_s);
}

// ---------- op GEMM accumulate: x += hg @ op_W[l] + op_b[l]
template <typename T>
__device__ void gemmop_body(const float* hg, const T* opW, const T* opb, float* x,
                            int l, float (*xs)[HD]) {
  int row0 = blockIdx.x * GROWS; int t = threadIdx.x;
  #pragma unroll
  for (int r = 0; r < GROWS; ++r) xs[r][t] = hg[(row0 + r) * HD + t];
  __syncthreads();
  const T* W = opW + l * HD * HD;
  float acc[GROWS];
  #pragma unroll
  for (int r = 0; r < GROWS; ++r) acc[r] = 0.f;
  for (int k = 0; k < HD; ++k) {
    float w = ldv(W, k * HD + t);
    #pragma unroll
    for (int r = 0; r < GROWS; ++r) acc[r] += xs[r][k] * w;
  }
  float bias = ldv(opb, l * HD + t);
  #pragma unroll
  for (int r = 0; r < GROWS; ++r) x[(row0 + r) * HD + t] += acc[r] + bias;
}
__global__ void __launch_bounds__(256) k_gemm_op(const float* hg, const void* opW, const void* opb,
                          float* x, int l, const int* flag) {
  __shared__ float xs[GROWS][HD];
  if (*flag) gemmop_body<bf16>(hg, (const bf16*)opW, (const bf16*)opb, x, l, xs);
  else gemmop_body<float>(hg, (const float*)opW, (const float*)opb, x, l, xs);
}

// ---------- heads
template <typename T>
__device__ void heads_body(const float* x,
                           const T* cardW, const T* cardb, const T* atW, const T* atb,
                           const T* srcW, const T* srcb, const T* tgtW, const T* tgtb,
                           const T* v1W, const T* v1b, const T* v2W, const T* v2b,
                           T* out, float* sge, float* sh1) {
  int b = blockIdx.x, t = threadIdx.x;
  float acc = 0.f;
  for (int s = 0; s < NS; ++s) acc += x[(b * NS + s) * HD + t];
  sge[t] = acc * (1.f / NS);
  __syncthreads();
  for (int p = t; p < NC + 3 + NS + NS; p += 256) {
    if (p < NC) {
      int col = p;
      float o = ldv(cardb, col);
      for (int k = 0; k < HD; ++k) o += sge[k] * ldv(cardW, k * NC + col);
      stv(out, b * NC + col, o);
    } else if (p < NC + 3) {
      int col = p - NC;
      float o = ldv(atb, col);
      for (int k = 0; k < HD; ++k) o += sge[k] * ldv(atW, k * 3 + col);
      stv(out, B * NC + b * 3 + col, o);
    } else if (p < NC + 3 + NS) {
      int col = p - NC - 3;
      float o = ldv(srcb, col);
      for (int k = 0; k < HD; ++k) o += sge[k] * ldv(srcW, k * NS + col);
      stv(out, B * NC + B * 3 + b * NS + col, o);
    } else {
      int col = p - NC - 3 - NS;
      float o = ldv(tgtb, col);
      for (int k = 0; k < HD; ++k) o += sge[k] * ldv(tgtW, k * NS + col);
      stv(out, B * NC + B * 3 + B * NS + b * NS + col, o);
    }
  }
  if (t < 128) {
    float o = ldv(v1b, t);
    for (int k = 0; k < HD; ++k) o += sge[k] * ldv(v1W, k * 128 + t);
    sh1[t] = fmaxf(o, 0.f);
  }
  __syncthreads();
  if (t < 64) {
    float pv = sh1[t] * ldv(v2W, t) + sh1[t + 64] * ldv(v2W, t + 64);
    #pragma unroll
    for (int o = 32; o > 0; o >>= 1) pv += __shfl_xor(pv, o);
    if (t == 0) stv(out, B * (NC + 3 + NS + NS) + b, tanhf(pv + ldv(v2b, 0)));
  }
}
__global__ void __launch_bounds__(256) k_heads(const float* x,
                        const void* cardW, const void* cardb, const void* atW, const void* atb,
                        const void* srcW, const void* srcb, const void* tgtW, const void* tgtb,
                        const void* v1W, const void* v1b, const void* v2W, const void* v2b,
                        void* out, const int* flag) {
  __shared__ float sge[HD];
  __shared__ float sh1[128];
  if (*flag) heads_body<bf16>(x, (const bf16*)cardW, (const bf16*)cardb, (const bf16*)atW,
                              (const bf16*)atb, (const bf16*)srcW, (const bf16*)srcb,
                              (const bf16*)tgtW, (const bf16*)tgtb, (const bf16*)v1W,
                              (const bf16*)v1b, (const bf16*)v2W, (const bf16*)v2b,
                              (bf16*)out, sge, sh1);
  else heads_body<float>(x, (const float*)cardW, (const float*)cardb, (const float*)atW,
                         (const float*)atb, (const float*)srcW, (const float*)srcb,
                         (const float*)tgtW, (const float*)tgtb, (const float*)v1W,
                         (const float*)v1b, (const float*)v2W, (const float*)v2b,
                         (float*)out, sge, sh1);
}

extern "C" void kernel_launch(void* const* d_in, const int* in_sizes, int n_in,
                              void* d_out, int out_size, void* d_ws, size_t ws_size,
                              hipStream_t stream) {
  const void* spatial = d_in[0];
  const void* cardctx = d_in[1];
  const void* adj = d_in[2];
  const void* ctxW = d_in[3]; const void* ctxb = d_in[4];
  const void* lncs = d_in[5]; const void* lncb = d_in[6];
  const void* inW = d_in[7];  const void* inb = d_in[8];
  const void* lnps = d_in[9]; const void* lnpb = d_in[10];
  const void* cpW = d_in[11]; const void* cpb = d_in[12];
  const void* Wl = d_in[13];  const void* Wr = d_in[14]; const void* Wa = d_in[15];
  const void* opW = d_in[16]; const void* opb = d_in[17];
  const void* cardW = d_in[18]; const void* cardb = d_in[19];
  const void* atW = d_in[20];   const void* atb = d_in[21];
  const void* srcW = d_in[22];  const void* srcb = d_in[23];
  const void* tgtW = d_in[24];  const void* tgtb = d_in[25];
  const void* v1W = d_in[26];   const void* v1b = d_in[27];
  const void* v2W = d_in[28];   const void* v2b = d_in[29];

  int* flag = (int*)d_ws;
  float* base = (float*)((char*)d_ws + 256);
  float* g  = base;               // B*HD
  float* c  = g + B * HD;         // B*HD
  float* x  = c + B * HD;         // B*NS*HD
  float* h  = x + B * NS * HD;    // B*NS*HD (reused as hg)
  float* hl = h + B * NS * HD;    // B*NS*HD
  float* hr = hl + B * NS * HD;   // B*NS*HD
  float* hg = h;                  // alias: h is dead once hl/hr exist

  k_detect<<<1, 64, 0, stream>>>(adj, flag);
  k_ctx<<<B, HD, 0, stream>>>(cardctx, ctxW, ctxb, lncs, lncb, g, flag);
  k_inproj<<<B * NS, HD, 0, stream>>>(spatial, inW, inb, x, flag);
  for (int l = 0; l < NL; ++l) {
    k_cproj<<<B, HD, 0, stream>>>(g, cpW, cpb, c, l, flag);
    k_lnadd<<<B * NS, HD, 0, stream>>>(x, c, lnps, lnpb, h, l, flag);
    k_gemm_lr<<<B * NS / GROWS, HD, 0, stream>>>(h, Wl, Wr, hl, hr, l, flag);
    k_gat<<<B * NH, 256, 0, stream>>>(hl, hr, adj, Wa, hg, l, flag);
    k_gemm_op<<<B * NS / GROWS, HD, 0, stream>>>(hg, opW, opb, x, l, flag);
  }
  k_heads<<<B, HD, 0, stream>>>(x, cardW, cardb, atW, atb, srcW, srcb, tgtW, tgtb,
                                v1W, v1b, v2W, v2b, d_out, flag);
}